// Round 1
// baseline (128.580 us; speedup 1.0000x reference)
//
#include <hip/hip_runtime.h>
#include <math.h>

#define HB 256   // hidden
#define UB 128   // attention units
#define BB 16    // batch
#define TD 128   // decoder steps
#define TE 1024  // encoder steps

#define TT 4     // t-rows per score block
#define SC 64    // s-chunk staged in LDS
#define NCH (TE / SC)  // 16 chunks

// exp(2*clamp(w,-30,30)) : staged operand for tanh factorization
__device__ __forceinline__ float exp2w(float w) {
    float t = fminf(fmaxf(w, -30.f), 30.f);
    return __expf(2.f * t);
}

// out[row, u] = exp(2*(sum_h X[row,h]*W[h,u] + bias[u]))  (clamped)
template<int RPB>
__global__ __launch_bounds__(UB) void proj_exp_kernel(
    const float* __restrict__ X, const float* __restrict__ W,
    const float* __restrict__ bias, float* __restrict__ out) {
    __shared__ float xs[RPB][HB];
    const int u = threadIdx.x;            // 0..127
    const long row0 = (long)blockIdx.x * RPB;

    // stage RPB input rows (RPB*HB floats) via float4
    const float4* src = reinterpret_cast<const float4*>(X + row0 * HB);
    float4* dst = reinterpret_cast<float4*>(&xs[0][0]);
    constexpr int NV = RPB * HB / 4;
    #pragma unroll
    for (int i = 0; i < NV / UB; ++i) dst[i * UB + u] = src[i * UB + u];
    __syncthreads();

    float acc[RPB];
    #pragma unroll
    for (int r = 0; r < RPB; ++r) acc[r] = 0.f;
    for (int h = 0; h < HB; ++h) {
        float w = W[h * UB + u];          // coalesced across u
        #pragma unroll
        for (int r = 0; r < RPB; ++r) acc[r] = fmaf(xs[r][h], w, acc[r]);
    }
    const float bb = bias[u];
    #pragma unroll
    for (int r = 0; r < RPB; ++r) {
        out[(row0 + r) * UB + u] = exp2w(acc[r] + bb);
    }
}

// scores + fused row softmax.
// score_eff[t,s] = -2 * sum_u V[u] / (Ea[t,u]*Eb[s,u] + 1)
// (the dropped "+sum(V)+bv" is constant per row -> softmax invariant)
__global__ __launch_bounds__(256) void score_softmax_kernel(
    const float* __restrict__ Ea,   // [B*TD, UB]
    const float* __restrict__ Eb,   // [B*TE, UB]
    const float* __restrict__ V,    // [UB]
    float* __restrict__ out) {      // [B, TD, TE]
    __shared__ float w1s[TT][UB];       // 2 KB
    __shared__ float w2s[SC][UB + 4];   // 33.8 KB, stride 132 -> conflict-free b128
    __shared__ float vs[UB];            // 0.5 KB

    const int tid = threadIdx.x;
    const int b  = blockIdx.x / (TD / TT);
    const int t0 = (blockIdx.x % (TD / TT)) * TT;

    const float* w1p = Ea + ((long)b * TD + t0) * UB;
    for (int i = tid; i < TT * UB; i += 256) w1s[i / UB][i % UB] = w1p[i];
    if (tid < UB) vs[tid] = V[tid];

    const int tl = tid >> 6;   // 0..3 : t within tile (uniform per wave)
    const int sl = tid & 63;   // 0..63: s within chunk
    const float* w2base = Eb + (long)b * TE * UB;

    float sc[NCH];
    for (int c = 0; c < NCH; ++c) {
        __syncthreads();   // protect previous chunk (and w1s/vs on c==0)
        const float4* src = reinterpret_cast<const float4*>(w2base + (long)c * SC * UB);
        #pragma unroll
        for (int i = 0; i < (SC * UB / 4) / 256; ++i) {   // 8 float4 per thread
            int idx = i * 256 + tid;
            int r = idx >> 5;       // UB/4 = 32 float4 per row
            int col = idx & 31;
            reinterpret_cast<float4*>(&w2s[r][0])[col] = src[idx];
        }
        __syncthreads();

        float acc = 0.f;
        #pragma unroll
        for (int u = 0; u < UB; u += 4) {
            float4 a  = *reinterpret_cast<const float4*>(&w1s[tl][u]);  // broadcast
            float4 e  = *reinterpret_cast<const float4*>(&w2s[sl][u]);  // per-lane
            float4 vv = *reinterpret_cast<const float4*>(&vs[u]);       // broadcast
            acc = fmaf(vv.x, __builtin_amdgcn_rcpf(fmaf(a.x, e.x, 1.f)), acc);
            acc = fmaf(vv.y, __builtin_amdgcn_rcpf(fmaf(a.y, e.y, 1.f)), acc);
            acc = fmaf(vv.z, __builtin_amdgcn_rcpf(fmaf(a.z, e.z, 1.f)), acc);
            acc = fmaf(vv.w, __builtin_amdgcn_rcpf(fmaf(a.w, e.w, 1.f)), acc);
        }
        sc[c] = -2.f * acc;
    }

    // row softmax: row t0+tl lives entirely in this wave (64 lanes x NCH regs)
    float m = sc[0];
    #pragma unroll
    for (int c = 1; c < NCH; ++c) m = fmaxf(m, sc[c]);
    #pragma unroll
    for (int off = 32; off > 0; off >>= 1) m = fmaxf(m, __shfl_xor(m, off, 64));
    float sum = 0.f;
    #pragma unroll
    for (int c = 0; c < NCH; ++c) { sc[c] = __expf(sc[c] - m); sum += sc[c]; }
    #pragma unroll
    for (int off = 32; off > 0; off >>= 1) sum += __shfl_xor(sum, off, 64);
    const float inv = 1.f / sum;

    float* orow = out + ((long)b * TD + (t0 + tl)) * TE;
    #pragma unroll
    for (int c = 0; c < NCH; ++c) orow[sl + SC * c] = sc[c] * inv;  // coalesced
}

extern "C" void kernel_launch(void* const* d_in, const int* in_sizes, int n_in,
                              void* d_out, int out_size, void* d_ws, size_t ws_size,
                              hipStream_t stream) {
    const float* dec = (const float*)d_in[0];   // [B, TD, HB]
    const float* enc = (const float*)d_in[1];   // [B, TE, HB]
    const float* W1  = (const float*)d_in[2];   // [HB, UB]
    const float* b1  = (const float*)d_in[3];   // [UB]
    const float* W2  = (const float*)d_in[4];   // [HB, UB]
    const float* b2  = (const float*)d_in[5];   // [UB]
    const float* V   = (const float*)d_in[6];   // [UB, 1]
    // d_in[7] = bv : softmax-invariant, unused
    float* out = (float*)d_out;

    float* Ea = (float*)d_ws;                        // B*TD*UB = 1 MB
    float* Eb = Ea + (long)BB * TD * UB;             // B*TE*UB = 8 MB

    proj_exp_kernel<16><<<BB * TD / 16, UB, 0, stream>>>(dec, W1, b1, Ea);
    proj_exp_kernel<16><<<BB * TE / 16, UB, 0, stream>>>(enc, W2, b2, Eb);
    score_softmax_kernel<<<BB * (TD / TT), 256, 0, stream>>>(Ea, Eb, V, out);
}

// Round 2
// 83.402 us; speedup vs baseline: 1.5417x; 1.5417x over previous
//
#include <hip/hip_runtime.h>
#include <math.h>

#define HB 256   // hidden
#define UB 128   // attention units
#define BB 16    // batch
#define TD 128   // decoder steps
#define TE 1024  // encoder steps
#define TT 4     // t-rows per score block (register-resident)

// exp(2*clamp(w,-30,30)) : staged operand for tanh factorization
// tanh(a+e) = 1 - 2/(exp(2a)exp(2e)+1)
__device__ __forceinline__ float exp2c(float w) {
    float t = fminf(fmaxf(w, -30.f), 30.f);
    return __expf(2.f * t);
}

// P[row,u] = exp(2*(sum_h X[row,h] W[h,u] + bias[u]))   (clamped)
// TRANS=0: out[row*UB+u]            (dec path, Ea)
// TRANS=1: out[(b*UB+u)*seq + s]    (enc path, EbT; b=row/seq, s=row%seq)
// Block: 128 threads = 2 waves; wave0 owns u=0..63, wave1 u=64..127.
// Thread computes RPB output rows for its single u column:
// per 4-h group: 4 coalesced W dword loads + RPB broadcast ds_read_b128
// + 4*RPB FMA  ->  4 FMA per LDS issue slot (VALU-bound).
template<int RPB, int TRANS>
__global__ __launch_bounds__(128) void proj_exp2(
    const float* __restrict__ X, const float* __restrict__ W,
    const float* __restrict__ bias, float* __restrict__ out, int seq) {
    __shared__ float xs[RPB][HB];
    const int tid = threadIdx.x;
    const int ul  = tid;                  // u = 0..127 (wave0 low half, wave1 high)
    const long row0 = (long)blockIdx.x * RPB;

    // stage RPB input rows via float4 (coalesced)
    const float4* src = reinterpret_cast<const float4*>(X + row0 * HB);
    float4* dst = reinterpret_cast<float4*>(&xs[0][0]);
    constexpr int NV = RPB * HB / 4;
    #pragma unroll
    for (int i = 0; i < NV / 128; ++i) dst[i * 128 + tid] = src[i * 128 + tid];
    __syncthreads();

    float acc[RPB];
    #pragma unroll
    for (int r = 0; r < RPB; ++r) acc[r] = 0.f;

    for (int h = 0; h < HB; h += 4) {
        float wv[4];
        #pragma unroll
        for (int k = 0; k < 4; ++k) wv[k] = W[(h + k) * UB + ul];  // coalesced, L1/L2-hot
        #pragma unroll
        for (int r = 0; r < RPB; ++r) {
            float4 x4 = *reinterpret_cast<const float4*>(&xs[r][h]);  // wave-uniform broadcast
            acc[r] = fmaf(x4.x, wv[0], acc[r]);
            acc[r] = fmaf(x4.y, wv[1], acc[r]);
            acc[r] = fmaf(x4.z, wv[2], acc[r]);
            acc[r] = fmaf(x4.w, wv[3], acc[r]);
        }
    }
    const float bb = bias[ul];
    if (TRANS == 0) {
        #pragma unroll
        for (int r = 0; r < RPB; ++r)
            out[(row0 + r) * UB + ul] = exp2c(acc[r] + bb);
    } else {
        const long b  = row0 / seq;
        const long s0 = row0 % seq;
        float* op = out + ((b * UB) + ul) * (long)seq + s0;  // 16-float contiguous run
        #pragma unroll
        for (int r = 0; r < RPB; r += 4) {
            float4 v = make_float4(exp2c(acc[r + 0] + bb), exp2c(acc[r + 1] + bb),
                                   exp2c(acc[r + 2] + bb), exp2c(acc[r + 3] + bb));
            *reinterpret_cast<float4*>(op + r) = v;
        }
    }
}

// scores + fused block softmax, no LDS in the main loop.
// score_eff[t,s] = -2 * sum_u V[u] / (Ea[t,u]*EbT[u,s] + 1)   (row-const dropped)
// Block: 512 thr = 8 waves; wave w owns s in [128w,128w+128), lane l -> s=128w+2l{,+1}.
// TT=4 t-rows kept in registers so each coalesced EbT float2 load feeds 8 FMA+4 rcp.
__global__ __launch_bounds__(512) void score_softmax2(
    const float* __restrict__ Ea,   // [B*TD, UB]
    const float* __restrict__ EbT,  // [B, UB, TE]
    const float* __restrict__ V,    // [UB]
    float* __restrict__ out) {      // [B, TD, TE]
    const int tid = threadIdx.x;
    const int w = tid >> 6;
    const int l = tid & 63;

    // XCD-bijective swizzle: grid=512, xcd=i%8 gets b in {2*xcd, 2*xcd+1}
    // -> per-XCD EbT working set = 1 MB (fits 4 MB L2).
    const int i   = blockIdx.x;
    const int xcd = i & 7;
    const int j   = i >> 3;              // 0..63
    const int b   = 2 * xcd + (j >> 5);
    const int t0  = (j & 31) * TT;

    const float* __restrict__ ap = Ea + ((long)b * TD + t0) * UB;      // wave-uniform
    const float* __restrict__ eb = EbT + ((long)b * UB) * TE + (w * 128 + 2 * l);

    float acc[TT][2];
    #pragma unroll
    for (int t = 0; t < TT; ++t) { acc[t][0] = 0.f; acc[t][1] = 0.f; }

    #pragma unroll 2
    for (int u = 0; u < UB; u += 4) {
        float vv[4], a[TT][4];
        float4 v4 = *reinterpret_cast<const float4*>(V + u);           // uniform
        vv[0] = v4.x; vv[1] = v4.y; vv[2] = v4.z; vv[3] = v4.w;
        #pragma unroll
        for (int t = 0; t < TT; ++t) {
            float4 a4 = *reinterpret_cast<const float4*>(ap + t * UB + u);  // uniform
            a[t][0] = a4.x; a[t][1] = a4.y; a[t][2] = a4.z; a[t][3] = a4.w;
        }
        #pragma unroll
        for (int k = 0; k < 4; ++k) {
            float2 e = *reinterpret_cast<const float2*>(eb + (long)(u + k) * TE);  // coalesced 512B/wave
            #pragma unroll
            for (int t = 0; t < TT; ++t) {
                acc[t][0] = fmaf(vv[k], __builtin_amdgcn_rcpf(fmaf(a[t][k], e.x, 1.f)), acc[t][0]);
                acc[t][1] = fmaf(vv[k], __builtin_amdgcn_rcpf(fmaf(a[t][k], e.y, 1.f)), acc[t][1]);
            }
        }
    }

    float sc[TT][2];
    #pragma unroll
    for (int t = 0; t < TT; ++t) { sc[t][0] = -2.f * acc[t][0]; sc[t][1] = -2.f * acc[t][1]; }

    // block softmax: row t is spread over 8 waves -> LDS cross-wave reduce
    __shared__ float red[TT][8];
    float m[TT];
    #pragma unroll
    for (int t = 0; t < TT; ++t) {
        float x = fmaxf(sc[t][0], sc[t][1]);
        #pragma unroll
        for (int off = 32; off > 0; off >>= 1) x = fmaxf(x, __shfl_xor(x, off, 64));
        if (l == 0) red[t][w] = x;
    }
    __syncthreads();
    #pragma unroll
    for (int t = 0; t < TT; ++t) {
        m[t] = red[t][0];
        #pragma unroll
        for (int k = 1; k < 8; ++k) m[t] = fmaxf(m[t], red[t][k]);
    }
    __syncthreads();
    float sum[TT];
    #pragma unroll
    for (int t = 0; t < TT; ++t) {
        sc[t][0] = __expf(sc[t][0] - m[t]);
        sc[t][1] = __expf(sc[t][1] - m[t]);
        float s = sc[t][0] + sc[t][1];
        #pragma unroll
        for (int off = 32; off > 0; off >>= 1) s += __shfl_xor(s, off, 64);
        if (l == 0) red[t][w] = s;
    }
    __syncthreads();
    #pragma unroll
    for (int t = 0; t < TT; ++t) {
        float s = red[t][0];
        #pragma unroll
        for (int k = 1; k < 8; ++k) s += red[t][k];
        const float inv = 1.f / s;
        float2 o = make_float2(sc[t][0] * inv, sc[t][1] * inv);
        *reinterpret_cast<float2*>(out + ((long)b * TD + t0 + t) * TE + w * 128 + 2 * l) = o;
    }
}

extern "C" void kernel_launch(void* const* d_in, const int* in_sizes, int n_in,
                              void* d_out, int out_size, void* d_ws, size_t ws_size,
                              hipStream_t stream) {
    const float* dec = (const float*)d_in[0];   // [B, TD, HB]
    const float* enc = (const float*)d_in[1];   // [B, TE, HB]
    const float* W1  = (const float*)d_in[2];   // [HB, UB]
    const float* b1  = (const float*)d_in[3];   // [UB]
    const float* W2  = (const float*)d_in[4];   // [HB, UB]
    const float* b2  = (const float*)d_in[5];   // [UB]
    const float* V   = (const float*)d_in[6];   // [UB, 1]
    // d_in[7] = bv : softmax-invariant, unused
    float* out = (float*)d_out;

    float* Ea  = (float*)d_ws;                       // [B*TD, UB]  1 MB
    float* EbT = Ea + (long)BB * TD * UB;            // [B, UB, TE] 8 MB

    proj_exp2<8, 0><<<BB * TD / 8, 128, 0, stream>>>(dec, W1, b1, Ea, TD);
    proj_exp2<16, 1><<<BB * TE / 16, 128, 0, stream>>>(enc, W2, b2, EbT, TE);
    score_softmax2<<<BB * (TD / TT), 512, 0, stream>>>(Ea, EbT, V, out);
}